// Round 9
// baseline (99.361 us; speedup 1.0000x reference)
//
#include <hip/hip_runtime.h>

typedef unsigned short u16;
typedef u16 u16x8 __attribute__((ext_vector_type(8)));
typedef __bf16 bf16x8 __attribute__((ext_vector_type(8)));
typedef float f32x4 __attribute__((ext_vector_type(4)));

#define MFMA16 __builtin_amdgcn_mfma_f32_16x16x32_bf16

__device__ __forceinline__ u16 f2bf(float f) {
  unsigned u = __builtin_bit_cast(unsigned, f);
  u += 0x7FFFu + ((u >> 16) & 1u);
  return (u16)(u >> 16);
}

// XOR-swizzled LDS byte address for 64-bf16 (128B) rows (guide G4).
__device__ __forceinline__ int swz(int row, int bcol) {
  return row * 128 + (bcol ^ ((row & 7) << 4));
}

__device__ __forceinline__ void gl16(const u16* g, u16* l) {
  __builtin_amdgcn_global_load_lds(
      (const __attribute__((address_space(1))) unsigned int*)g,
      (__attribute__((address_space(3))) unsigned int*)l, 16, 0, 0);
}

// raw workgroup barrier (no forced vmcnt(0) drain)
__device__ __forceinline__ void BARR() {
  asm volatile("" ::: "memory");
  __builtin_amdgcn_s_barrier();
  asm volatile("" ::: "memory");
}
#define VMCNT(n) asm volatile("s_waitcnt vmcnt(" #n ")" ::: "memory")
#define LGKM0 asm volatile("s_waitcnt lgkmcnt(0)" ::: "memory")
#define LGKMH asm volatile("s_waitcnt lgkmcnt(8)" ::: "memory")
#define SCHED0 __builtin_amdgcn_sched_barrier(0)
#define FENCE asm volatile("" ::: "memory")

// ---------------------------------------------------------------------------
// Flattened fp32 -> bf16 cast. 16M elements total, 8/thread, 8192 blocks.
// ws layout (u16): Wq 0 | Wk 1M | Wv 2M | Wo 3M | Xq 4M | Xk 8M | Xv 12M
// ---------------------------------------------------------------------------
__global__ __launch_bounds__(256)
void cast_all(const float* __restrict__ q, const float* __restrict__ k,
              const float* __restrict__ v, const float* __restrict__ wq,
              const float* __restrict__ wk, const float* __restrict__ wv,
              const float* __restrict__ wo, u16* __restrict__ ws) {
  const long i = ((long)blockIdx.x * 256 + threadIdx.x) * 8;
  const float* s;
  u16* d;
  if (i < 12582912) {  // X region (12M)
    const int seg = (int)(i >> 22);
    const float* xs = (seg == 0) ? q : (seg == 1) ? k : v;
    s = xs + (i & 4194303);
    d = ws + 4194304 + i;
  } else {  // weights (4M)
    const long j = i - 12582912;
    const int seg = (int)(j >> 20);
    const float* wsrc = (seg == 0) ? wq : (seg == 1) ? wk : (seg == 2) ? wv : wo;
    s = wsrc + (j & 1048575);
    d = ws + j;
  }
  float4 v0 = *(const float4*)s;
  float4 v1 = *(const float4*)(s + 4);
  u16x8 p = {f2bf(v0.x), f2bf(v0.y), f2bf(v0.z), f2bf(v0.w),
             f2bf(v1.x), f2bf(v1.y), f2bf(v1.z), f2bf(v1.w)};
  *(u16x8*)d = p;
}

// ---------------------------------------------------------------------------
// QKV projection — m201-style 8-phase schedule, 256x256 tile, BK=64, 8 waves.
// Waves 2M x 4N (wm=w>>2, wn=w&3); per-wave C = 128x64 = 8x4 frags.
// LDS 128 KB: A[buf][half] 4x16KB at 0; B[buf][half] at 64KB.
//   A-half h = tile rows with bit6==h (each wave's quadrant mh reads half mh).
//   B-half h = tile cols with bit5==h (quadrant nh reads half nh).
// Per K-tile t (buf=t&1), 4 phases, each:
//   [stage 1 half-tile (2 gl16/wave)] ; ds_reads ; bar ; lgkm0+sched_barrier ;
//   setprio1 ; 16 MFMA (quadrant) ; setprio0 ; vmcnt(6) ; bar
// Stage schedule: ph1: B-hi[t+1] ; ph2: A-lo[t+2] ; ph3: A-hi[t+1] ;
//                 ph4: B-lo[t+2]   (all verified vs read/free ledger).
// vmcnt(6) leaves the 3 newest half-tiles in flight -> retires the half
// staged 4 phases ago, exactly when the next phase first reads it. Tail:
// t=14 ph2/ph4 -> vmcnt(4); t=15 ph1 -> vmcnt(2), ph2 -> vmcnt(0).
// Prologue: A-lo0,B-lo0,B-hi0,A-hi0,A-lo1,B-lo1 ; vmcnt(4) ; barrier.
// ---------------------------------------------------------------------------
__global__ __launch_bounds__(512)
void qkv8ph(const u16* __restrict__ ws_in, const float* __restrict__ c0,
            const float* __restrict__ c1, const float* __restrict__ c2,
            u16* __restrict__ o0, u16* __restrict__ o1,
            u16* __restrict__ o2) {
  const int bid = blockIdx.x;
  const int s = (bid & 7) * 24 + (bid >> 3);  // XCD-bijective, 192 % 8 == 0
  const int z = s >> 6;
  const int rem = s & 63;
  const int m0 = (rem >> 2) << 8;  // 16 m-tiles
  const int n0 = (rem & 3) << 8;   // 4 n-tiles

  const u16* __restrict__ A = ws_in + 4194304 + z * 4194304;
  const u16* __restrict__ W = ws_in + z * 1048576;
  const float* Bi = (z == 0) ? c0 : (z == 1) ? c1 : c2;
  u16* O = (z == 0) ? o0 : (z == 1) ? o1 : o2;

  const int tid = threadIdx.x, lane = tid & 63, w = tid >> 6;
  const int wm = w >> 2, wn = w & 3;
  const int r = lane & 15, g = lane >> 4;

  __shared__ u16 SH[65536];  // 128 KB
  char* sb = (char*)SH;

  f32x4 acc[8][4] = {};
  bf16x8 af[2][4], bf[2][2];

  // staging addressing: q8 = covered row-within-64 (wave w, lane>>3);
  // inverse-swizzled source column (rule 21), linear LDS dest.
  const int q8 = (w << 3) + (lane >> 3);
  const int ce = ((lane & 7) ^ (lane >> 3)) << 3;

  // SA(t,h): A rows {j*128 + h*64 + q8}, j=0,1 -> A[buf][h] + j*8K + w*1K
#define SA(tt, h)                                                           \
  {                                                                         \
    FENCE;                                                                  \
    gl16(A + (m0 + (h)*64 + q8) * 1024 + (tt)*64 + ce,                      \
         (u16*)(sb + (((tt)&1) << 15) + ((h) << 14) + (w << 10)));          \
    gl16(A + (m0 + 128 + (h)*64 + q8) * 1024 + (tt)*64 + ce,                \
         (u16*)(sb + (((tt)&1) << 15) + ((h) << 14) + 8192 + (w << 10)));   \
    FENCE;                                                                  \
  }
  // SB(t,h): B cols {((j*2+(q8>>5))<<6) + h*32 + (q8&31)}
#define SB(tt, h)                                                           \
  {                                                                         \
    FENCE;                                                                  \
    gl16(W + (n0 + (((q8 >> 5)) << 6) + (h)*32 + (q8 & 31)) * 1024 +        \
             (tt)*64 + ce,                                                  \
         (u16*)(sb + 65536 + (((tt)&1) << 15) + ((h) << 14) + (w << 10)));  \
    gl16(W + (n0 + ((2 + (q8 >> 5)) << 6) + (h)*32 + (q8 & 31)) * 1024 +    \
             (tt)*64 + ce,                                                  \
         (u16*)(sb + 65536 + (((tt)&1) << 15) + ((h) << 14) + 8192 +        \
                (w << 10)));                                                \
    FENCE;                                                                  \
  }

  const int colk0 = (g * 16) ^ ((r & 7) << 4);
  const int colk1 = (64 + g * 16) ^ ((r & 7) << 4);
  const int rowA = (wm * 64 + r) * 128;  // + fi*2048 within half
  const int rowB = (wn * 32 + r) * 128;  // + n2*2048 within half

#define LDSA(h)                                                             \
  _Pragma("unroll") for (int fi = 0; fi < 4; ++fi) {                        \
    char* p = sb + bo + ((h) << 14) + rowA + fi * 2048;                     \
    af[0][fi] = __builtin_bit_cast(bf16x8, *(const u16x8*)(p + colk0));     \
    af[1][fi] = __builtin_bit_cast(bf16x8, *(const u16x8*)(p + colk1));     \
  }
#define LDSB(h)                                                             \
  _Pragma("unroll") for (int n2 = 0; n2 < 2; ++n2) {                        \
    char* p = sb + 65536 + bo + ((h) << 14) + rowB + n2 * 2048;             \
    bf[0][n2] = __builtin_bit_cast(bf16x8, *(const u16x8*)(p + colk0));     \
    bf[1][n2] = __builtin_bit_cast(bf16x8, *(const u16x8*)(p + colk1));     \
  }
#define FMAQ(mh, nh)                                                        \
  __builtin_amdgcn_s_setprio(1);                                            \
  _Pragma("unroll") for (int fi = 0; fi < 4; ++fi)                          \
  _Pragma("unroll") for (int n2 = 0; n2 < 2; ++n2) {                        \
    acc[(mh)*4 + fi][(nh)*2 + n2] = MFMA16(                                 \
        af[0][fi], bf[0][n2], acc[(mh)*4 + fi][(nh)*2 + n2], 0, 0, 0);      \
    acc[(mh)*4 + fi][(nh)*2 + n2] = MFMA16(                                 \
        af[1][fi], bf[1][n2], acc[(mh)*4 + fi][(nh)*2 + n2], 0, 0, 0);      \
  }                                                                         \
  __builtin_amdgcn_s_setprio(0);

  // prologue: tile0 complete + A-lo1, B-lo1 in flight
  SA(0, 0);
  SB(0, 0);
  SB(0, 1);
  SA(0, 1);
  SA(1, 0);
  SB(1, 0);
  VMCNT(4);
  __builtin_amdgcn_s_barrier();
  FENCE;

#pragma unroll 1
  for (int t = 0; t < 16; ++t) {
    const int bo = (t & 1) << 15;
    // ---- phase 1: quadrant (0,0) — A-lo x B-lo
    if (t < 15) SB(t + 1, 1);
    LDSA(0);
    LDSB(0);
    LGKMH;
    BARR();
    LGKM0;
    SCHED0;
    FMAQ(0, 0);
    if (t < 15) { VMCNT(6); } else { VMCNT(2); }
    BARR();
    // ---- phase 2: quadrant (0,1) — A-lo (regs) x B-hi
    if (t < 14) SA(t + 2, 0);
    LDSB(1);
    BARR();
    LGKM0;
    SCHED0;
    FMAQ(0, 1);
    if (t < 14) { VMCNT(6); } else if (t == 14) { VMCNT(4); } else { VMCNT(0); }
    BARR();
    // ---- phase 3: quadrant (1,0) — A-hi x B-lo (re-read)
    if (t < 15) SA(t + 1, 1);
    LDSA(1);
    LDSB(0);
    LGKMH;
    BARR();
    LGKM0;
    SCHED0;
    FMAQ(1, 0);
    if (t < 15) { VMCNT(6); }
    BARR();
    // ---- phase 4: quadrant (1,1) — A-hi (regs) x B-hi (re-read)
    if (t < 14) SB(t + 2, 0);
    LDSB(1);
    BARR();
    LGKM0;
    SCHED0;
    FMAQ(1, 1);
    if (t < 14) { VMCNT(6); } else if (t == 14) { VMCNT(4); }
    BARR();
  }

  // epilogue: C/D layout col=lane&15, row=g*4+q -> bf16 [B,H,S,64]
#pragma unroll
  for (int n = 0; n < 4; ++n) {
    const int gn = n0 + wn * 64 + (n >> 1) * 32 + (n & 1) * 16 + r;
    const int hh = gn >> 6, d = gn & 63;
    const float bv = Bi[gn];
#pragma unroll
    for (int m = 0; m < 8; ++m) {
#pragma unroll
      for (int q = 0; q < 4; ++q) {
        int gm = m0 + wm * 128 + (m >> 2) * 64 + (m & 3) * 16 + g * 4 + q;
        int bb = gm >> 11, sIdx = gm & 2047;
        O[((bb * 16 + hh) * 2048 + sIdx) * 64 + d] = f2bf(acc[m][n][q] + bv);
      }
    }
  }
#undef SA
#undef SB
#undef LDSA
#undef LDSB
#undef FMAQ
}

// ---------------------------------------------------------------------------
// 128x128 2-phase counted-vmcnt GEMM core (round-4/5-proven) — out proj.
// ---------------------------------------------------------------------------
#define OSTGA(tt, c, j)                                                     \
  gl16(Ain + (m0 + (c)*64 + (w << 4) + (j)*8 + (lane >> 3)) * 1024 +        \
           (tt)*64 + (((lane & 7) ^ (lane >> 3)) << 3),                     \
       (u16*)(sb + (((tt)&1) << 15) + (c)*8192 + (w << 11) + ((j) << 10)))
#define OSTGB(tt, c, j)                                                     \
  gl16(W + (n0 + (c)*64 + (w << 4) + (j)*8 + (lane >> 3)) * 1024 +          \
           (tt)*64 + (((lane & 7) ^ (lane >> 3)) << 3),                     \
       (u16*)(sb + (((tt)&1) << 15) + 16384 + (c)*8192 + (w << 11) +        \
              ((j) << 10)))
#define OLDA()                                                              \
  _Pragma("unroll") for (int m = 0; m < 4; ++m) {                           \
    char* p = sb + bo + rowAb + m * 16 * 128;                               \
    af[0][m] = __builtin_bit_cast(bf16x8, *(const u16x8*)(p + colr0));      \
    af[1][m] = __builtin_bit_cast(bf16x8, *(const u16x8*)(p + colr1));      \
  }
#define OLDB(n)                                                             \
  {                                                                         \
    char* p = sb + bo + rowBb + (n)*16 * 128;                               \
    bf[0][n] = __builtin_bit_cast(bf16x8, *(const u16x8*)(p + colr0));      \
    bf[1][n] = __builtin_bit_cast(bf16x8, *(const u16x8*)(p + colr1));      \
  }
#define OFMA(nh)                                                            \
  __builtin_amdgcn_s_setprio(1);                                            \
  _Pragma("unroll") for (int m = 0; m < 4; ++m)                             \
  _Pragma("unroll") for (int n = 0; n < 2; ++n) {                           \
    acc[m][(nh)*2 + n] =                                                    \
        MFMA16(af[0][m], bf[0][(nh)*2 + n], acc[m][(nh)*2 + n], 0, 0, 0);   \
    acc[m][(nh)*2 + n] =                                                    \
        MFMA16(af[1][m], bf[1][(nh)*2 + n], acc[m][(nh)*2 + n], 0, 0, 0);   \
  }                                                                         \
  __builtin_amdgcn_s_setprio(0);

__device__ __forceinline__ void core128(const u16* __restrict__ Ain,
                                        const u16* __restrict__ W, int m0,
                                        int n0, char* sb,
                                        f32x4 (&acc)[4][4]) {
  const int tid = threadIdx.x, lane = tid & 63, w = tid >> 6;
  const int wm = w >> 1, wn = w & 1;
  const int r = lane & 15, g = lane >> 4;
  bf16x8 af[2][4], bf[2][4];

  const int colr0 = (g * 16) ^ ((r & 7) << 4);
  const int colr1 = (64 + g * 16) ^ ((r & 7) << 4);
  const int rowAb = (wm * 64 + r) * 128;
  const int rowBb = 16384 + (wn * 64 + r) * 128;

#pragma unroll
  for (int c = 0; c < 2; ++c) { OSTGA(0, c, 0); OSTGA(0, c, 1); }
#pragma unroll
  for (int c = 0; c < 2; ++c) { OSTGB(0, c, 0); OSTGB(0, c, 1); }
#pragma unroll
  for (int c = 0; c < 2; ++c) { OSTGA(1, c, 0); OSTGA(1, c, 1); }
  VMCNT(4);
  __builtin_amdgcn_s_barrier();
  asm volatile("" ::: "memory");

  for (int t = 0; t < 16; ++t) {
    const int bo = (t & 1) << 15;
    if (t < 15) { OSTGB(t + 1, 0, 0); OSTGB(t + 1, 0, 1); OSTGB(t + 1, 1, 0); OSTGB(t + 1, 1, 1); }
    OLDA();
    OLDB(0); OLDB(1);
    OFMA(0);
    BARR();
    if (t < 14) { OSTGA(t + 2, 0, 0); OSTGA(t + 2, 0, 1); OSTGA(t + 2, 1, 0); OSTGA(t + 2, 1, 1); }
    OLDB(2); OLDB(3);
    OFMA(1);
    if (t < 14) { VMCNT(4); } else if (t == 14) { VMCNT(0); }
    BARR();
  }
}

__global__ __launch_bounds__(256)
void out_gemm_p(const u16* __restrict__ Ain2, const u16* __restrict__ W2,
                const float* __restrict__ Bi, float* __restrict__ C) {
  const int bid = blockIdx.x;
  const int s = (bid & 7) * 32 + (bid >> 3);  // 256 % 8 == 0
  const int m0 = (s >> 3) << 7, n0 = (s & 7) << 7;

  const int tid = threadIdx.x, lane = tid & 63, w = tid >> 6;
  const int wm = w >> 1, wn = w & 1;
  const int r = lane & 15, g = lane >> 4;

  __shared__ u16 SH[32768];  // 64 KB
  f32x4 acc[4][4] = {};
  core128(Ain2, W2, m0, n0, (char*)SH, acc);

#pragma unroll
  for (int m = 0; m < 4; ++m) {
#pragma unroll
    for (int n = 0; n < 4; ++n) {
      int gn = n0 + wn * 64 + n * 16 + r;
      float bv = Bi[gn];
#pragma unroll
      for (int q = 0; q < 4; ++q) {
        int gm = m0 + wm * 64 + m * 16 + g * 4 + q;
        C[gm * 1024 + gn] = acc[m][n][q] + bv;
      }
    }
  }
}

// ---------------------------------------------------------------------------
// Sparse flash attention (r8 version, T14 async-stage + dbuf K/V).
// ---------------------------------------------------------------------------
__global__ __launch_bounds__(256)
void attn_kernel(const u16* __restrict__ Q, const u16* __restrict__ K,
                 const u16* __restrict__ V, u16* __restrict__ O) {
  const int qt = blockIdx.x, h = blockIdx.y, b = blockIdx.z;
  const int tid = threadIdx.x, lane = tid & 63, w = tid >> 6;
  const int r = lane & 15, g = lane >> 4;
  const int q0 = qt * 64;
  const int base = (b * 16 + h) * 131072;
  const u16* Qb = Q + base;

  __shared__ u16 Ks[2][4096];
  __shared__ u16 Vt[2][4096];  // transposed: Vt[d][j]
  __shared__ u16 Pl[4608];     // 4 waves x 16 rows x 144B stride

  bf16x8 qf[2];
  {
    const u16* qp = Qb + (q0 + w * 16 + r) * 64 + g * 8;
    qf[0] = __builtin_bit_cast(bf16x8, *(const u16x8*)qp);
    qf[1] = __builtin_bit_cast(bf16x8, *(const u16x8*)(qp + 32));
  }

  f32x4 acc[4] = {};
  float m_run[4] = {-1e30f, -1e30f, -1e30f, -1e30f};
  float l_run[4] = {};

  const int nt = (qt <= 3) ? (qt + 1) : 4;
  const int srow = tid >> 3, sc = (tid & 7) * 8;
  const u16* Kg = K + base + srow * 64 + sc;
  const u16* Vg = V + base + srow * 64 + sc;

  u16x8 krA[2], vrA[2], krB[2], vrB[2];
  krA[0] = *(const u16x8*)(Kg);
  krA[1] = *(const u16x8*)(Kg + 2048);
  vrA[0] = *(const u16x8*)(Vg);
  vrA[1] = *(const u16x8*)(Vg + 2048);

#pragma unroll
  for (int tix = 0; tix < 4; ++tix) {
    if (tix < nt) {
      const int j0 = ((tix == 0) ? 0 : ((qt <= 3) ? tix : (qt - 3 + tix))) * 64;
      const int bo = (tix & 1) * 8192;
      if ((tix & 1) == 0) {
#pragma unroll
        for (int i = 0; i < 2; ++i) {
          int row = i * 32 + srow;
          *(u16x8*)((char*)Ks + bo + swz(row, sc * 2)) = krA[i];
#pragma unroll
          for (int qq = 0; qq < 8; ++qq) {
            int d = sc + qq;
            *(u16*)((char*)Vt + bo + d * 128 + ((2 * row) ^ ((d & 7) << 4))) =
                vrA[i][qq];
          }
        }
      } else {
#pragma unroll
        for (int i = 0; i < 2; ++i) {
          int row = i * 32 + srow;
          *(u16x8*)((char*)Ks + bo + swz(row, sc * 2)) = krB[i];
#pragma unroll
          for (int qq = 0; qq < 8; ++qq) {
            int d = sc + qq;
            *(u16*)((char*)Vt + bo + d * 128 + ((2 * row) ^ ((d & 7) << 4))) =
                vrB[i][qq];
          }
        }
      }
      if (tix + 1 < nt) {
        const int jn = (((qt <= 3) ? (tix + 1) : (qt - 2 + tix)) * 64) * 64;
        if ((tix & 1) == 0) {
          krB[0] = *(const u16x8*)(Kg + jn);
          krB[1] = *(const u16x8*)(Kg + jn + 2048);
          vrB[0] = *(const u16x8*)(Vg + jn);
          vrB[1] = *(const u16x8*)(Vg + jn + 2048);
        } else {
          krA[0] = *(const u16x8*)(Kg + jn);
          krA[1] = *(const u16x8*)(Kg + jn + 2048);
          vrA[0] = *(const u16x8*)(Vg + jn);
          vrA[1] = *(const u16x8*)(Vg + jn + 2048);
        }
      }
      LGKM0;
      BARR();

      f32x4 S[4] = {};
#pragma unroll
      for (int kk = 0; kk < 2; ++kk)
#pragma unroll
        for (int n = 0; n < 4; ++n) {
          bf16x8 kf = __builtin_bit_cast(
              bf16x8, *(const u16x8*)((char*)Ks + bo +
                                      swz(n * 16 + r, kk * 64 + g * 16)));
          S[n] = MFMA16(qf[kk], kf, S[n], 0, 0, 0);
        }

      float mloc[4] = {-1e30f, -1e30f, -1e30f, -1e30f};
#pragma unroll
      for (int n = 0; n < 4; ++n) {
        int j = j0 + n * 16 + r;
#pragma unroll
        for (int q = 0; q < 4; ++q) {
          int i = q0 + w * 16 + g * 4 + q;
          bool ok = (j <= i) && (((i - j) <= 128) || (j < 16));
          float s = ok ? S[n][q] * 0.125f : -1e30f;
          S[n][q] = s;
          mloc[q] = fmaxf(mloc[q], s);
        }
      }
#pragma unroll
      for (int q = 0; q < 4; ++q)
#pragma unroll
        for (int off = 1; off < 16; off <<= 1)
          mloc[q] = fmaxf(mloc[q], __shfl_xor(mloc[q], off));

      float alpha[4], rsum[4] = {};
#pragma unroll
      for (int q = 0; q < 4; ++q) {
        float mn = fmaxf(m_run[q], mloc[q]);
        alpha[q] = __expf(m_run[q] - mn);
        m_run[q] = mn;
      }
#pragma unroll
      for (int n = 0; n < 4; ++n)
#pragma unroll
        for (int q = 0; q < 4; ++q) {
          float p = __expf(S[n][q] - m_run[q]);
          S[n][q] = p;
          rsum[q] += p;
        }
#pragma unroll
      for (int q = 0; q < 4; ++q) {
#pragma unroll
        for (int off = 1; off < 16; off <<= 1)
          rsum[q] += __shfl_xor(rsum[q], off);
        l_run[q] = l_run[q] * alpha[q] + rsum[q];
      }
#pragma unroll
      for (int n = 0; n < 4; ++n) {
        acc[n][0] *= alpha[0];
        acc[n][1] *= alpha[1];
        acc[n][2] *= alpha[2];
        acc[n][3] *= alpha[3];
      }

#pragma unroll
      for (int n = 0; n < 4; ++n)
#pragma unroll
        for (int q = 0; q < 4; ++q)
          *((u16*)((char*)Pl + w * 2304 + (g * 4 + q) * 144) + (n * 16 + r)) =
              f2bf(S[n][q]);

#pragma unroll
      for (int kk = 0; kk < 2; ++kk) {
        bf16x8 pf = __builtin_bit_cast(
            bf16x8, *(const u16x8*)((char*)Pl + w * 2304 + r * 144 + kk * 64 +
                                    g * 16));
#pragma unroll
        for (int n = 0; n < 4; ++n) {
          bf16x8 vf = __builtin_bit_cast(
              bf16x8, *(const u16x8*)((char*)Vt + bo +
                                      swz(n * 16 + r, kk * 64 + g * 16)));
          acc[n] = MFMA16(pf, vf, acc[n], 0, 0, 0);
        }
      }
    }
  }

#pragma unroll
  for (int n = 0; n < 4; ++n)
#pragma unroll
    for (int q = 0; q < 4; ++q) {
      int s = q0 + w * 16 + g * 4 + q;
      int d = n * 16 + r;
      O[(b * 2048 + s) * 1024 + h * 64 + d] = f2bf(acc[n][q] / l_run[q]);
    }
}

// ---------------------------------------------------------------------------
extern "C" void kernel_launch(void* const* d_in, const int* in_sizes, int n_in,
                              void* d_out, int out_size, void* d_ws,
                              size_t ws_size, hipStream_t stream) {
  const float* b_q = (const float*)d_in[4];
  const float* b_k = (const float*)d_in[6];
  const float* b_v = (const float*)d_in[8];
  const float* b_o = (const float*)d_in[10];

  u16* ws = (u16*)d_ws;
  // ws (u16): Wq 0 | Wk 1M | Wv 2M | Wo 3M | Xq 4M | Xk 8M | Xv 12M |
  //           Qw 16M | Kw 20M | Vw 24M | Aw aliases Xq (4M)
  u16* Qw = ws + 16777216;
  u16* Kw = ws + 20971520;
  u16* Vw = ws + 25165824;
  u16* Aw = ws + 4194304;  // aliases Xq (dead after qkv projection)

  cast_all<<<dim3(8192), dim3(256), 0, stream>>>(
      (const float*)d_in[0], (const float*)d_in[1], (const float*)d_in[2],
      (const float*)d_in[3], (const float*)d_in[5], (const float*)d_in[7],
      (const float*)d_in[9], ws);
  qkv8ph<<<dim3(192), dim3(512), 0, stream>>>(ws, b_q, b_k, b_v, Qw, Kw, Vw);
  attn_kernel<<<dim3(32, 16, 2), dim3(256), 0, stream>>>(Qw, Kw, Vw, Aw);
  out_gemm_p<<<dim3(256), dim3(256), 0, stream>>>(Aw, ws + 3145728, b_o,
                                                  (float*)d_out);
}

// Round 10
// 95.542 us; speedup vs baseline: 1.0400x; 1.0400x over previous
//
#include <hip/hip_runtime.h>

typedef unsigned short u16;
typedef u16 u16x8 __attribute__((ext_vector_type(8)));
typedef __bf16 bf16x8 __attribute__((ext_vector_type(8)));
typedef float f32x4 __attribute__((ext_vector_type(4)));

#define MFMA16 __builtin_amdgcn_mfma_f32_16x16x32_bf16

__device__ __forceinline__ u16 f2bf(float f) {
  unsigned u = __builtin_bit_cast(unsigned, f);
  u += 0x7FFFu + ((u >> 16) & 1u);
  return (u16)(u >> 16);
}

// XOR-swizzled LDS byte address for 64-bf16 (128B) rows (guide G4).
__device__ __forceinline__ int swz(int row, int bcol) {
  return row * 128 + (bcol ^ ((row & 7) << 4));
}

__device__ __forceinline__ void gl16(const u16* g, u16* l) {
  __builtin_amdgcn_global_load_lds(
      (const __attribute__((address_space(1))) unsigned int*)g,
      (__attribute__((address_space(3))) unsigned int*)l, 16, 0, 0);
}

// raw workgroup barrier (no forced vmcnt(0) drain)
__device__ __forceinline__ void BARR() {
  asm volatile("" ::: "memory");
  __builtin_amdgcn_s_barrier();
  asm volatile("" ::: "memory");
}
#define VMCNT(n) asm volatile("s_waitcnt vmcnt(" #n ")" ::: "memory")

// ---------------------------------------------------------------------------
// Flattened fp32 -> bf16 cast. 16M elements total, 8/thread, 8192 blocks.
// ws layout (u16): Wq 0 | Wk 1M | Wv 2M | Wo 3M | Xq 4M | Xk 8M | Xv 12M
// ---------------------------------------------------------------------------
__global__ __launch_bounds__(256)
void cast_all(const float* __restrict__ q, const float* __restrict__ k,
              const float* __restrict__ v, const float* __restrict__ wq,
              const float* __restrict__ wk, const float* __restrict__ wv,
              const float* __restrict__ wo, u16* __restrict__ ws) {
  const long i = ((long)blockIdx.x * 256 + threadIdx.x) * 8;
  const float* s;
  u16* d;
  if (i < 12582912) {  // X region (12M)
    const int seg = (int)(i >> 22);
    const float* xs = (seg == 0) ? q : (seg == 1) ? k : v;
    s = xs + (i & 4194303);
    d = ws + 4194304 + i;
  } else {  // weights (4M)
    const long j = i - 12582912;
    const int seg = (int)(j >> 20);
    const float* wsrc = (seg == 0) ? wq : (seg == 1) ? wk : (seg == 2) ? wv : wo;
    s = wsrc + (j & 1048575);
    d = ws + j;
  }
  float4 v0 = *(const float4*)s;
  float4 v1 = *(const float4*)(s + 4);
  u16x8 p = {f2bf(v0.x), f2bf(v0.y), f2bf(v0.z), f2bf(v0.w),
             f2bf(v1.x), f2bf(v1.y), f2bf(v1.z), f2bf(v1.w)};
  *(u16x8*)d = p;
}

// ---------------------------------------------------------------------------
// Shared 128x128 2-phase counted-vmcnt GEMM core (round-4/5-proven).
// ---------------------------------------------------------------------------
#define OSTGA(tt, c, j)                                                     \
  gl16(Ain + (m0 + (c)*64 + (w << 4) + (j)*8 + (lane >> 3)) * 1024 +        \
           (tt)*64 + (((lane & 7) ^ (lane >> 3)) << 3),                     \
       (u16*)(sb + (((tt)&1) << 15) + (c)*8192 + (w << 11) + ((j) << 10)))
#define OSTGB(tt, c, j)                                                     \
  gl16(W + (n0 + (c)*64 + (w << 4) + (j)*8 + (lane >> 3)) * 1024 +          \
           (tt)*64 + (((lane & 7) ^ (lane >> 3)) << 3),                     \
       (u16*)(sb + (((tt)&1) << 15) + 16384 + (c)*8192 + (w << 11) +        \
              ((j) << 10)))
#define OLDA()                                                              \
  _Pragma("unroll") for (int m = 0; m < 4; ++m) {                           \
    char* p = sb + bo + rowAb + m * 16 * 128;                               \
    af[0][m] = __builtin_bit_cast(bf16x8, *(const u16x8*)(p + colr0));      \
    af[1][m] = __builtin_bit_cast(bf16x8, *(const u16x8*)(p + colr1));      \
  }
#define OLDB(n)                                                             \
  {                                                                         \
    char* p = sb + bo + rowBb + (n)*16 * 128;                               \
    bf[0][n] = __builtin_bit_cast(bf16x8, *(const u16x8*)(p + colr0));      \
    bf[1][n] = __builtin_bit_cast(bf16x8, *(const u16x8*)(p + colr1));      \
  }
#define OFMA(nh)                                                            \
  __builtin_amdgcn_s_setprio(1);                                            \
  _Pragma("unroll") for (int m = 0; m < 4; ++m)                             \
  _Pragma("unroll") for (int n = 0; n < 2; ++n) {                           \
    acc[m][(nh)*2 + n] =                                                    \
        MFMA16(af[0][m], bf[0][(nh)*2 + n], acc[m][(nh)*2 + n], 0, 0, 0);   \
    acc[m][(nh)*2 + n] =                                                    \
        MFMA16(af[1][m], bf[1][(nh)*2 + n], acc[m][(nh)*2 + n], 0, 0, 0);   \
  }                                                                         \
  __builtin_amdgcn_s_setprio(0);

__device__ __forceinline__ void core128(const u16* __restrict__ Ain,
                                        const u16* __restrict__ W, int m0,
                                        int n0, char* sb,
                                        f32x4 (&acc)[4][4]) {
  const int tid = threadIdx.x, lane = tid & 63, w = tid >> 6;
  const int wm = w >> 1, wn = w & 1;
  const int r = lane & 15, g = lane >> 4;
  bf16x8 af[2][4], bf[2][4];

  const int colr0 = (g * 16) ^ ((r & 7) << 4);
  const int colr1 = (64 + g * 16) ^ ((r & 7) << 4);
  const int rowAb = (wm * 64 + r) * 128;
  const int rowBb = 16384 + (wn * 64 + r) * 128;

#pragma unroll
  for (int c = 0; c < 2; ++c) { OSTGA(0, c, 0); OSTGA(0, c, 1); }
#pragma unroll
  for (int c = 0; c < 2; ++c) { OSTGB(0, c, 0); OSTGB(0, c, 1); }
#pragma unroll
  for (int c = 0; c < 2; ++c) { OSTGA(1, c, 0); OSTGA(1, c, 1); }
  VMCNT(4);
  __builtin_amdgcn_s_barrier();
  asm volatile("" ::: "memory");

  for (int t = 0; t < 16; ++t) {
    const int bo = (t & 1) << 15;
    if (t < 15) { OSTGB(t + 1, 0, 0); OSTGB(t + 1, 0, 1); OSTGB(t + 1, 1, 0); OSTGB(t + 1, 1, 1); }
    OLDA();
    OLDB(0); OLDB(1);
    OFMA(0);
    BARR();
    if (t < 14) { OSTGA(t + 2, 0, 0); OSTGA(t + 2, 0, 1); OSTGA(t + 2, 1, 0); OSTGA(t + 2, 1, 1); }
    OLDB(2); OLDB(3);
    OFMA(1);
    if (t < 14) { VMCNT(4); } else if (t == 14) { VMCNT(0); }
    BARR();
  }
}

// ---------------------------------------------------------------------------
// QKV projection: 768 blocks (3 z * 32 m * 8 n), 128x128 tile, 2 blocks/CU.
// ---------------------------------------------------------------------------
__global__ __launch_bounds__(256)
void qkv_gemm128(const u16* __restrict__ ws_in, const float* __restrict__ c0,
                 const float* __restrict__ c1, const float* __restrict__ c2,
                 u16* __restrict__ o0, u16* __restrict__ o1,
                 u16* __restrict__ o2) {
  const int bid = blockIdx.x;
  const int s = (bid & 7) * 96 + (bid >> 3);  // XCD-contiguous, 768 % 8 == 0
  const int z = s >> 8;
  const int rem = s & 255;
  const int m0 = (rem >> 3) << 7, n0 = (rem & 7) << 7;

  const u16* __restrict__ Ain = ws_in + 4194304 + z * 4194304;
  const u16* __restrict__ W = ws_in + z * 1048576;
  const float* Bi = (z == 0) ? c0 : (z == 1) ? c1 : c2;
  u16* O = (z == 0) ? o0 : (z == 1) ? o1 : o2;

  const int tid = threadIdx.x, lane = tid & 63, w = tid >> 6;
  const int wm = w >> 1, wn = w & 1;
  const int r = lane & 15, g = lane >> 4;

  __shared__ u16 SH[32768];  // 64 KB
  f32x4 acc[4][4] = {};
  core128(Ain, W, m0, n0, (char*)SH, acc);

  // epilogue -> bf16 [B,H,S,64]; C/D layout col=lane&15, row=g*4+q
#pragma unroll
  for (int n = 0; n < 4; ++n) {
    const int gn = n0 + wn * 64 + n * 16 + r;
    const int hh = gn >> 6, d = gn & 63;
    const float bv = Bi[gn];
#pragma unroll
    for (int m = 0; m < 4; ++m) {
#pragma unroll
      for (int q = 0; q < 4; ++q) {
        int gm = m0 + wm * 64 + m * 16 + g * 4 + q;
        int bb = gm >> 11, sIdx = gm & 2047;
        O[((bb * 16 + hh) * 2048 + sIdx) * 64 + d] = f2bf(acc[m][n][q] + bv);
      }
    }
  }
}

// ---------------------------------------------------------------------------
// Output projection: 256 blocks, 128x128 tile, fp32 out.
// ---------------------------------------------------------------------------
__global__ __launch_bounds__(256)
void out_gemm_p(const u16* __restrict__ Ain2, const u16* __restrict__ W2,
                const float* __restrict__ Bi, float* __restrict__ C) {
  const int bid = blockIdx.x;
  const int s = (bid & 7) * 32 + (bid >> 3);  // 256 % 8 == 0
  const int m0 = (s >> 3) << 7, n0 = (s & 7) << 7;

  const int tid = threadIdx.x, lane = tid & 63, w = tid >> 6;
  const int wm = w >> 1, wn = w & 1;
  const int r = lane & 15, g = lane >> 4;

  __shared__ u16 SH[32768];  // 64 KB
  f32x4 acc[4][4] = {};
  core128(Ain2, W2, m0, n0, (char*)SH, acc);

#pragma unroll
  for (int m = 0; m < 4; ++m) {
#pragma unroll
    for (int n = 0; n < 4; ++n) {
      int gn = n0 + wn * 64 + n * 16 + r;
      float bv = Bi[gn];
#pragma unroll
      for (int q = 0; q < 4; ++q) {
        int gm = m0 + wm * 64 + m * 16 + g * 4 + q;
        C[gm * 1024 + gn] = acc[m][n][q] + bv;
      }
    }
  }
}

// ---------------------------------------------------------------------------
// V transpose: Vw [B,H,S,64] -> VT [B,H,64,S]. grid (32 j-tiles, 32 bh).
// LDS 64x72 u16 with chunk swizzle (c8 ^= row>>3) for conflict-free gather.
// ---------------------------------------------------------------------------
__global__ __launch_bounds__(256)
void vt_trans(const u16* __restrict__ Vw, u16* __restrict__ VT) {
  const int jt = blockIdx.x, bh = blockIdx.y;
  const u16* src = Vw + bh * 131072 + jt * 4096;  // 64 rows x 64, contiguous
  u16* dst = VT + bh * 131072 + jt * 64;          // rows d (stride 2048)
  __shared__ u16 Lt[64 * 72];
  const int t = threadIdx.x;
#pragma unroll
  for (int c2 = 0; c2 < 2; ++c2) {
    int c = t + c2 * 256;  // 0..511
    int row = c >> 3, col8 = c & 7;
    u16x8 v = *(const u16x8*)(src + row * 64 + col8 * 8);
    *(u16x8*)(Lt + row * 72 + ((col8 ^ (row >> 3)) * 8)) = v;
  }
  __syncthreads();
#pragma unroll
  for (int c2 = 0; c2 < 2; ++c2) {
    int c = t + c2 * 256;
    int d = c >> 3, j8 = c & 7;
    u16x8 o;
#pragma unroll
    for (int i = 0; i < 8; ++i) {
      int j = j8 * 8 + i;
      o[i] = Lt[j * 72 + (((d >> 3) ^ (j >> 3)) * 8) + (d & 7)];
    }
    *(u16x8*)(dst + d * 2048 + j8 * 8) = o;
  }
}

// ---------------------------------------------------------------------------
// Sparse flash attention v3: K and pre-transposed V staged via
// global_load_lds (zero staging VALU / scalar LDS writes), double-buffered,
// one raw barrier + vmcnt(0) per tile, setprio on MFMA clusters.
// grid (32 qtiles, 16 heads, 2 batch), 256 threads (4 waves x 16 q-rows).
// Tiles per q-tile: {0} ∪ {qt-2, qt-1, qt}. Mask: j<=i && (i-j<=128 || j<16).
// ---------------------------------------------------------------------------
__global__ __launch_bounds__(256)
void attn3(const u16* __restrict__ Q, const u16* __restrict__ K,
           const u16* __restrict__ VT, u16* __restrict__ O) {
  const int qt = blockIdx.x, h = blockIdx.y, b = blockIdx.z;
  const int tid = threadIdx.x, lane = tid & 63, w = tid >> 6;
  const int r = lane & 15, g = lane >> 4;
  const int q0 = qt * 64;
  const int base = (b * 16 + h) * 131072;
  const u16* Qb = Q + base;
  const u16* Kb = K + base;   // [j][64] rows, tile at j0 contiguous 8KB
  const u16* Vb = VT + base;  // [d][2048] rows

  __shared__ u16 Ks[2][4096];
  __shared__ u16 Vs[2][4096];
  __shared__ u16 Pl[4608];  // 4 waves x 16 rows x 144B stride

  bf16x8 qf[2];
  {
    const u16* qp = Qb + (q0 + w * 16 + r) * 64 + g * 8;
    qf[0] = __builtin_bit_cast(bf16x8, *(const u16x8*)qp);
    qf[1] = __builtin_bit_cast(bf16x8, *(const u16x8*)(qp + 32));
  }

  f32x4 acc[4] = {};
  float m_run[4] = {-1e30f, -1e30f, -1e30f, -1e30f};
  float l_run[4] = {};
  const int nt = (qt <= 3) ? (qt + 1) : 4;

  // staging: per wave chunks c = w and w+4 (chunk = 8 rows x 128B); source
  // col inverse-swizzled (rule 21), LDS dest linear -> swz() reads match.
  const int srow = lane >> 3;                       // row within chunk
  const int scol = ((lane & 7) ^ (lane >> 3)) * 8;  // u16 source col
#define STG(jv, buf)                                                        \
  {                                                                         \
    asm volatile("" ::: "memory");                                          \
    _Pragma("unroll") for (int cc = 0; cc < 2; ++cc) {                      \
      const int c = w + cc * 4;                                             \
      gl16(Kb + (jv)*64 + c * 512 + srow * 64 + scol, &Ks[buf][c * 512]);   \
      gl16(Vb + (c * 8 + srow) * 2048 + (jv) + scol, &Vs[buf][c * 512]);    \
    }                                                                       \
    asm volatile("" ::: "memory");                                          \
  }

  // prologue: tile 0 (j0 = 0)
  STG(0, 0);
  VMCNT(0);
  __builtin_amdgcn_s_barrier();
  asm volatile("" ::: "memory");

  for (int tix = 0; tix < nt; ++tix) {
    const int j0 = ((tix == 0) ? 0 : ((qt <= 3) ? tix : (qt - 3 + tix))) * 64;
    const int bo = (tix & 1) * 8192;  // byte offset into Ks/Vs
    // issue next tile's staging into the other buffer (stays in flight)
    if (tix + 1 < nt) {
      const int jn = ((qt <= 3) ? (tix + 1) : (qt - 2 + tix)) * 64;
      STG(jn, (tix + 1) & 1);
    }

    // ---- S = Q K^T
    f32x4 S[4] = {};
    __builtin_amdgcn_s_setprio(1);
#pragma unroll
    for (int kk = 0; kk < 2; ++kk)
#pragma unroll
      for (int n = 0; n < 4; ++n) {
        bf16x8 kf = __builtin_bit_cast(
            bf16x8, *(const u16x8*)((char*)Ks + bo +
                                    swz(n * 16 + r, kk * 64 + g * 16)));
        S[n] = MFMA16(qf[kk], kf, S[n], 0, 0, 0);
      }
    __builtin_amdgcn_s_setprio(0);

    float mloc[4] = {-1e30f, -1e30f, -1e30f, -1e30f};
#pragma unroll
    for (int n = 0; n < 4; ++n) {
      int j = j0 + n * 16 + r;
#pragma unroll
      for (int q = 0; q < 4; ++q) {
        int i = q0 + w * 16 + g * 4 + q;
        bool ok = (j <= i) && (((i - j) <= 128) || (j < 16));
        float s = ok ? S[n][q] * 0.125f : -1e30f;
        S[n][q] = s;
        mloc[q] = fmaxf(mloc[q], s);
      }
    }
#pragma unroll
    for (int q = 0; q < 4; ++q)
#pragma unroll
      for (int off = 1; off < 16; off <<= 1)
        mloc[q] = fmaxf(mloc[q], __shfl_xor(mloc[q], off));

    float alpha[4], rsum[4] = {};
#pragma unroll
    for (int q = 0; q < 4; ++q) {
      float mn = fmaxf(m_run[q], mloc[q]);
      alpha[q] = __expf(m_run[q] - mn);
      m_run[q] = mn;
    }
#pragma unroll
    for (int n = 0; n < 4; ++n)
#pragma unroll
      for (int q = 0; q < 4; ++q) {
        float p = __expf(S[n][q] - m_run[q]);
        S[n][q] = p;
        rsum[q] += p;
      }
#pragma unroll
    for (int q = 0; q < 4; ++q) {
#pragma unroll
      for (int off = 1; off < 16; off <<= 1)
        rsum[q] += __shfl_xor(rsum[q], off);
      l_run[q] = l_run[q] * alpha[q] + rsum[q];
    }
#pragma unroll
    for (int n = 0; n < 4; ++n) {
      acc[n][0] *= alpha[0];
      acc[n][1] *= alpha[1];
      acc[n][2] *= alpha[2];
      acc[n][3] *= alpha[3];
    }

    // P (bf16) -> per-wave LDS staging (wave-private region)
#pragma unroll
    for (int n = 0; n < 4; ++n)
#pragma unroll
      for (int q = 0; q < 4; ++q)
        *((u16*)((char*)Pl + w * 2304 + (g * 4 + q) * 144) + (n * 16 + r)) =
            f2bf(S[n][q]);

    // ---- O += P V  (B-operand from pre-transposed Vs)
    __builtin_amdgcn_s_setprio(1);
#pragma unroll
    for (int kk = 0; kk < 2; ++kk) {
      bf16x8 pf = __builtin_bit_cast(
          bf16x8,
          *(const u16x8*)((char*)Pl + w * 2304 + r * 144 + kk * 64 + g * 16));
#pragma unroll
      for (int n = 0; n < 4; ++n) {
        bf16x8 vf = __builtin_bit_cast(
            bf16x8, *(const u16x8*)((char*)Vs + bo +
                                    swz(n * 16 + r, kk * 64 + g * 16)));
        acc[n] = MFMA16(pf, vf, acc[n], 0, 0, 0);
      }
    }
    __builtin_amdgcn_s_setprio(0);

    VMCNT(0);  // next tile's staging has landed (issued before compute)
    BARR();
  }

#pragma unroll
  for (int n = 0; n < 4; ++n)
#pragma unroll
    for (int q = 0; q < 4; ++q) {
      int s = q0 + w * 16 + g * 4 + q;
      int d = n * 16 + r;
      O[(b * 2048 + s) * 1024 + h * 64 + d] = f2bf(acc[n][q] / l_run[q]);
    }
#undef STG
}

// ---------------------------------------------------------------------------
extern "C" void kernel_launch(void* const* d_in, const int* in_sizes, int n_in,
                              void* d_out, int out_size, void* d_ws,
                              size_t ws_size, hipStream_t stream) {
  const float* b_q = (const float*)d_in[4];
  const float* b_k = (const float*)d_in[6];
  const float* b_v = (const float*)d_in[8];
  const float* b_o = (const float*)d_in[10];

  u16* ws = (u16*)d_ws;
  // ws (u16): Wq 0 | Wk 1M | Wv 2M | Wo 3M | Xq 4M | Xk 8M | Xv 12M |
  //           Qw 16M | Kw 20M | Vw 24M
  // Aliases after qkv: Aw = Xq region (4M); VTw = Xk region (8M).
  u16* Qw = ws + 16777216;
  u16* Kw = ws + 20971520;
  u16* Vw = ws + 25165824;
  u16* Aw = ws + 4194304;
  u16* VTw = ws + 8388608;

  cast_all<<<dim3(8192), dim3(256), 0, stream>>>(
      (const float*)d_in[0], (const float*)d_in[1], (const float*)d_in[2],
      (const float*)d_in[3], (const float*)d_in[5], (const float*)d_in[7],
      (const float*)d_in[9], ws);
  qkv_gemm128<<<dim3(768), dim3(256), 0, stream>>>(ws, b_q, b_k, b_v, Qw, Kw,
                                                   Vw);
  vt_trans<<<dim3(32, 32), dim3(256), 0, stream>>>(Vw, VTw);
  attn3<<<dim3(32, 16, 2), dim3(256), 0, stream>>>(Qw, Kw, VTw, Aw);
  out_gemm_p<<<dim3(256), dim3(256), 0, stream>>>(Aw, ws + 3145728, b_o,
                                                  (float*)d_out);
}

// Round 12
// 89.833 us; speedup vs baseline: 1.1061x; 1.0635x over previous
//
#include <hip/hip_runtime.h>

typedef unsigned short u16;
typedef u16 u16x8 __attribute__((ext_vector_type(8)));
typedef __bf16 bf16x8 __attribute__((ext_vector_type(8)));
typedef float f32x4 __attribute__((ext_vector_type(4)));

#define MFMA16 __builtin_amdgcn_mfma_f32_16x16x32_bf16

__device__ __forceinline__ u16 f2bf(float f) {
  unsigned u = __builtin_bit_cast(unsigned, f);
  u += 0x7FFFu + ((u >> 16) & 1u);
  return (u16)(u >> 16);
}

// XOR-swizzled LDS byte address for 64-bf16 (128B) rows (guide G4).
__device__ __forceinline__ int swz(int row, int bcol) {
  return row * 128 + (bcol ^ ((row & 7) << 4));
}

__device__ __forceinline__ void gl16(const u16* g, u16* l) {
  __builtin_amdgcn_global_load_lds(
      (const __attribute__((address_space(1))) unsigned int*)g,
      (__attribute__((address_space(3))) unsigned int*)l, 16, 0, 0);
}

// raw workgroup barrier (no forced vmcnt(0) drain)
__device__ __forceinline__ void BARR() {
  asm volatile("" ::: "memory");
  __builtin_amdgcn_s_barrier();
  asm volatile("" ::: "memory");
}
#define VMCNT(n) asm volatile("s_waitcnt vmcnt(" #n ")" ::: "memory")
#define LGKM0 asm volatile("s_waitcnt lgkmcnt(0)" ::: "memory")

// ---------------------------------------------------------------------------
// Flattened fp32 -> bf16 cast. 16M elements total, 8/thread, 8192 blocks.
// ws layout (u16): Wq 0 | Wk 1M | Wv 2M | Wo 3M | Xq 4M | Xk 8M | Xv 12M
// ---------------------------------------------------------------------------
__global__ __launch_bounds__(256)
void cast_all(const float* __restrict__ q, const float* __restrict__ k,
              const float* __restrict__ v, const float* __restrict__ wq,
              const float* __restrict__ wk, const float* __restrict__ wv,
              const float* __restrict__ wo, u16* __restrict__ ws) {
  const long i = ((long)blockIdx.x * 256 + threadIdx.x) * 8;
  const float* s;
  u16* d;
  if (i < 12582912) {  // X region (12M)
    const int seg = (int)(i >> 22);
    const float* xs = (seg == 0) ? q : (seg == 1) ? k : v;
    s = xs + (i & 4194303);
    d = ws + 4194304 + i;
  } else {  // weights (4M)
    const long j = i - 12582912;
    const int seg = (int)(j >> 20);
    const float* wsrc = (seg == 0) ? wq : (seg == 1) ? wk : (seg == 2) ? wv : wo;
    s = wsrc + (j & 1048575);
    d = ws + j;
  }
  float4 v0 = *(const float4*)s;
  float4 v1 = *(const float4*)(s + 4);
  u16x8 p = {f2bf(v0.x), f2bf(v0.y), f2bf(v0.z), f2bf(v0.w),
             f2bf(v1.x), f2bf(v1.y), f2bf(v1.z), f2bf(v1.w)};
  *(u16x8*)d = p;
}

// ---------------------------------------------------------------------------
// Shared 128x128 2-phase counted-vmcnt GEMM core (round-4/5-proven) — qkv.
// ---------------------------------------------------------------------------
#define OSTGA(tt, c, j)                                                     \
  gl16(Ain + (m0 + (c)*64 + (w << 4) + (j)*8 + (lane >> 3)) * 1024 +        \
           (tt)*64 + (((lane & 7) ^ (lane >> 3)) << 3),                     \
       (u16*)(sb + (((tt)&1) << 15) + (c)*8192 + (w << 11) + ((j) << 10)))
#define OSTGB(tt, c, j)                                                     \
  gl16(W + (n0 + (c)*64 + (w << 4) + (j)*8 + (lane >> 3)) * 1024 +          \
           (tt)*64 + (((lane & 7) ^ (lane >> 3)) << 3),                     \
       (u16*)(sb + (((tt)&1) << 15) + 16384 + (c)*8192 + (w << 11) +        \
              ((j) << 10)))
#define OLDA()                                                              \
  _Pragma("unroll") for (int m = 0; m < 4; ++m) {                           \
    char* p = sb + bo + rowAb + m * 16 * 128;                               \
    af[0][m] = __builtin_bit_cast(bf16x8, *(const u16x8*)(p + colr0));      \
    af[1][m] = __builtin_bit_cast(bf16x8, *(const u16x8*)(p + colr1));      \
  }
#define OLDB(n)                                                             \
  {                                                                         \
    char* p = sb + bo + rowBb + (n)*16 * 128;                               \
    bf[0][n] = __builtin_bit_cast(bf16x8, *(const u16x8*)(p + colr0));      \
    bf[1][n] = __builtin_bit_cast(bf16x8, *(const u16x8*)(p + colr1));      \
  }
#define OFMA(nh)                                                            \
  __builtin_amdgcn_s_setprio(1);                                            \
  _Pragma("unroll") for (int m = 0; m < 4; ++m)                             \
  _Pragma("unroll") for (int n = 0; n < 2; ++n) {                           \
    acc[m][(nh)*2 + n] =                                                    \
        MFMA16(af[0][m], bf[0][(nh)*2 + n], acc[m][(nh)*2 + n], 0, 0, 0);   \
    acc[m][(nh)*2 + n] =                                                    \
        MFMA16(af[1][m], bf[1][(nh)*2 + n], acc[m][(nh)*2 + n], 0, 0, 0);   \
  }                                                                         \
  __builtin_amdgcn_s_setprio(0);

__device__ __forceinline__ void core128(const u16* __restrict__ Ain,
                                        const u16* __restrict__ W, int m0,
                                        int n0, char* sb,
                                        f32x4 (&acc)[4][4]) {
  const int tid = threadIdx.x, lane = tid & 63, w = tid >> 6;
  const int wm = w >> 1, wn = w & 1;
  const int r = lane & 15, g = lane >> 4;
  bf16x8 af[2][4], bf[2][4];

  const int colr0 = (g * 16) ^ ((r & 7) << 4);
  const int colr1 = (64 + g * 16) ^ ((r & 7) << 4);
  const int rowAb = (wm * 64 + r) * 128;
  const int rowBb = 16384 + (wn * 64 + r) * 128;

#pragma unroll
  for (int c = 0; c < 2; ++c) { OSTGA(0, c, 0); OSTGA(0, c, 1); }
#pragma unroll
  for (int c = 0; c < 2; ++c) { OSTGB(0, c, 0); OSTGB(0, c, 1); }
#pragma unroll
  for (int c = 0; c < 2; ++c) { OSTGA(1, c, 0); OSTGA(1, c, 1); }
  VMCNT(4);
  __builtin_amdgcn_s_barrier();
  asm volatile("" ::: "memory");

  for (int t = 0; t < 16; ++t) {
    const int bo = (t & 1) << 15;
    if (t < 15) { OSTGB(t + 1, 0, 0); OSTGB(t + 1, 0, 1); OSTGB(t + 1, 1, 0); OSTGB(t + 1, 1, 1); }
    OLDA();
    OLDB(0); OLDB(1);
    OFMA(0);
    BARR();
    if (t < 14) { OSTGA(t + 2, 0, 0); OSTGA(t + 2, 0, 1); OSTGA(t + 2, 1, 0); OSTGA(t + 2, 1, 1); }
    OLDB(2); OLDB(3);
    OFMA(1);
    if (t < 14) { VMCNT(4); } else if (t == 14) { VMCNT(0); }
    BARR();
  }
}

// ---------------------------------------------------------------------------
// QKV projection: 768 blocks (3 z * 32 m * 8 n), 128x128 tile, 2 blocks/CU.
// ---------------------------------------------------------------------------
__global__ __launch_bounds__(256)
void qkv_gemm128(const u16* __restrict__ ws_in, const float* __restrict__ c0,
                 const float* __restrict__ c1, const float* __restrict__ c2,
                 u16* __restrict__ o0, u16* __restrict__ o1,
                 u16* __restrict__ o2) {
  const int bid = blockIdx.x;
  const int s = (bid & 7) * 96 + (bid >> 3);  // XCD-contiguous, 768 % 8 == 0
  const int z = s >> 8;
  const int rem = s & 255;
  const int m0 = (rem >> 3) << 7, n0 = (rem & 7) << 7;

  const u16* __restrict__ Ain = ws_in + 4194304 + z * 4194304;
  const u16* __restrict__ W = ws_in + z * 1048576;
  const float* Bi = (z == 0) ? c0 : (z == 1) ? c1 : c2;
  u16* O = (z == 0) ? o0 : (z == 1) ? o1 : o2;

  const int tid = threadIdx.x, lane = tid & 63, w = tid >> 6;
  const int wm = w >> 1, wn = w & 1;
  const int r = lane & 15, g = lane >> 4;

  __shared__ u16 SH[32768];  // 64 KB
  f32x4 acc[4][4] = {};
  core128(Ain, W, m0, n0, (char*)SH, acc);

  // epilogue -> bf16 [B,H,S,64]; C/D layout col=lane&15, row=g*4+q
#pragma unroll
  for (int n = 0; n < 4; ++n) {
    const int gn = n0 + wn * 64 + n * 16 + r;
    const int hh = gn >> 6, d = gn & 63;
    const float bv = Bi[gn];
#pragma unroll
    for (int m = 0; m < 4; ++m) {
#pragma unroll
      for (int q = 0; q < 4; ++q) {
        int gm = m0 + wm * 64 + m * 16 + g * 4 + q;
        int bb = gm >> 11, sIdx = gm & 2047;
        O[((bb * 16 + hh) * 2048 + sIdx) * 64 + d] = f2bf(acc[m][n][q] + bv);
      }
    }
  }
}

// ---------------------------------------------------------------------------
// Output projection v2 (FIXED): 128x64 tile, 512 blocks, 48 KB LDS
// (3 blocks/CU capacity, whole grid resident). 4 waves (2m x 2n),
// per-wave C = 64x32, 16 MFMA/K-tile. Phases split by N (core128 invariant:
// A read ONLY in ph1, so ph2's A[t+2] staging into the same buf is 1 barrier
// past A's last reader — the r11 race is gone):
//  ph1: STG B[t+1] (2 gl16) | dsr A(8)+B-n0(2) | 8 MFMA (m x n0) | bar
//  ph2: STG A[t+2] (4 gl16) | dsr B-n1(2)      | 8 MFMA (m x n1) | vmcnt(4) | bar
// vmcnt(4): leaves A[t+2] (4 newest) in flight; retires A[t+1]+B[t+1].
// Tail: t=14 -> vmcnt(0); t=15 no stage/wait.
// Prologue: A0(4), B0(2), A1(4); vmcnt(4) retires A0+B0.
// ---------------------------------------------------------------------------
#define ZSTGA(tt, j)                                                        \
  gl16(Ain + (m0 + (w << 5) + (j)*8 + (lane >> 3)) * 1024 + (tt)*64 +       \
           (((lane & 7) ^ (lane >> 3)) << 3),                               \
       (u16*)(sb + ((tt)&1) * 24576 + (w << 12) + ((j) << 10)))
#define ZSTGB(tt, j)                                                        \
  gl16(W + (n0 + (w << 4) + (j)*8 + (lane >> 3)) * 1024 + (tt)*64 +         \
           (((lane & 7) ^ (lane >> 3)) << 3),                               \
       (u16*)(sb + ((tt)&1) * 24576 + 16384 + (w << 11) + ((j) << 10)))
#define ZLDA()                                                              \
  _Pragma("unroll") for (int m = 0; m < 4; ++m) {                           \
    char* p = sb + bo + rowAb + m * 2048;                                   \
    af[0][m] = __builtin_bit_cast(bf16x8, *(const u16x8*)(p + colr0));      \
    af[1][m] = __builtin_bit_cast(bf16x8, *(const u16x8*)(p + colr1));      \
  }
#define ZLDB(n)                                                             \
  {                                                                         \
    char* p = sb + bo + rowBb + (n)*2048;                                   \
    bf[0][n] = __builtin_bit_cast(bf16x8, *(const u16x8*)(p + colr0));      \
    bf[1][n] = __builtin_bit_cast(bf16x8, *(const u16x8*)(p + colr1));      \
  }
#define ZFMA(n)                                                             \
  __builtin_amdgcn_s_setprio(1);                                            \
  _Pragma("unroll") for (int m = 0; m < 4; ++m) {                           \
    acc[m][n] = MFMA16(af[0][m], bf[0][n], acc[m][n], 0, 0, 0);             \
    acc[m][n] = MFMA16(af[1][m], bf[1][n], acc[m][n], 0, 0, 0);             \
  }                                                                         \
  __builtin_amdgcn_s_setprio(0);

__global__ __launch_bounds__(256)
void out_gemm64(const u16* __restrict__ Ain, const u16* __restrict__ W,
                const float* __restrict__ Bi, float* __restrict__ C) {
  const int bid = blockIdx.x;
  const int s = (bid & 7) * 64 + (bid >> 3);  // XCD swizzle, 512 % 8 == 0
  const int m0 = (s >> 4) << 7;  // 32 m-tiles of 128
  const int n0 = (s & 15) << 6;  // 16 n-tiles of 64

  const int tid = threadIdx.x, lane = tid & 63, w = tid >> 6;
  const int wm = w >> 1, wn = w & 1;
  const int r = lane & 15, g = lane >> 4;

  __shared__ u16 SH[24576];  // 48 KB: 2 bufs x {A 16K | B 8K}
  char* sb = (char*)SH;

  f32x4 acc[4][2] = {};
  bf16x8 af[2][4], bf[2][2];

  const int colr0 = (g * 16) ^ ((r & 7) << 4);
  const int colr1 = (64 + g * 16) ^ ((r & 7) << 4);
  const int rowAb = (wm * 64 + r) * 128;
  const int rowBb = 16384 + (wn * 32 + r) * 128;

  // prologue: A0(4), B0(2), A1(4); A1 stays in flight
#pragma unroll
  for (int j = 0; j < 4; ++j) ZSTGA(0, j);
#pragma unroll
  for (int j = 0; j < 2; ++j) ZSTGB(0, j);
#pragma unroll
  for (int j = 0; j < 4; ++j) ZSTGA(1, j);
  VMCNT(4);
  __builtin_amdgcn_s_barrier();
  asm volatile("" ::: "memory");

  for (int t = 0; t < 16; ++t) {
    const int bo = (t & 1) * 24576;
    // ---- phase 1: all A + B-n0
    if (t < 15) { ZSTGB(t + 1, 0); ZSTGB(t + 1, 1); }
    ZLDA();
    ZLDB(0);
    ZFMA(0);
    BARR();
    // ---- phase 2: B-n1 only (A region not read -> A[t+2] staging safe)
    if (t < 14) { ZSTGA(t + 2, 0); ZSTGA(t + 2, 1); ZSTGA(t + 2, 2); ZSTGA(t + 2, 3); }
    ZLDB(1);
    ZFMA(1);
    if (t < 14) { VMCNT(4); } else if (t == 14) { VMCNT(0); }
    BARR();
  }

  // epilogue: fp32 C + bias
#pragma unroll
  for (int m = 0; m < 4; ++m) {
#pragma unroll
    for (int n = 0; n < 2; ++n) {
      int gn = n0 + wn * 32 + n * 16 + r;
      float bv = Bi[gn];
#pragma unroll
      for (int q = 0; q < 4; ++q) {
        int gm = m0 + wm * 64 + m * 16 + g * 4 + q;
        C[gm * 1024 + gn] = acc[m][n][q] + bv;
      }
    }
  }
}

// ---------------------------------------------------------------------------
// Sparse flash attention (r8 version, T14 async-stage + dbuf K/V).
// grid (32 qtiles, 16 heads, 2 batch), 256 threads (4 waves x 16 q-rows).
// ---------------------------------------------------------------------------
__global__ __launch_bounds__(256)
void attn_kernel(const u16* __restrict__ Q, const u16* __restrict__ K,
                 const u16* __restrict__ V, u16* __restrict__ O) {
  const int qt = blockIdx.x, h = blockIdx.y, b = blockIdx.z;
  const int tid = threadIdx.x, lane = tid & 63, w = tid >> 6;
  const int r = lane & 15, g = lane >> 4;
  const int q0 = qt * 64;
  const int base = (b * 16 + h) * 131072;
  const u16* Qb = Q + base;

  __shared__ u16 Ks[2][4096];
  __shared__ u16 Vt[2][4096];  // transposed: Vt[d][j]
  __shared__ u16 Pl[4608];     // 4 waves x 16 rows x 144B stride

  bf16x8 qf[2];
  {
    const u16* qp = Qb + (q0 + w * 16 + r) * 64 + g * 8;
    qf[0] = __builtin_bit_cast(bf16x8, *(const u16x8*)qp);
    qf[1] = __builtin_bit_cast(bf16x8, *(const u16x8*)(qp + 32));
  }

  f32x4 acc[4] = {};
  float m_run[4] = {-1e30f, -1e30f, -1e30f, -1e30f};
  float l_run[4] = {};

  const int nt = (qt <= 3) ? (qt + 1) : 4;
  const int srow = tid >> 3, sc = (tid & 7) * 8;
  const u16* Kg = K + base + srow * 64 + sc;
  const u16* Vg = V + base + srow * 64 + sc;

  u16x8 krA[2], vrA[2], krB[2], vrB[2];
  krA[0] = *(const u16x8*)(Kg);
  krA[1] = *(const u16x8*)(Kg + 2048);
  vrA[0] = *(const u16x8*)(Vg);
  vrA[1] = *(const u16x8*)(Vg + 2048);

#pragma unroll
  for (int tix = 0; tix < 4; ++tix) {
    if (tix < nt) {
      const int j0 = ((tix == 0) ? 0 : ((qt <= 3) ? tix : (qt - 3 + tix))) * 64;
      const int bo = (tix & 1) * 8192;
      if ((tix & 1) == 0) {
#pragma unroll
        for (int i = 0; i < 2; ++i) {
          int row = i * 32 + srow;
          *(u16x8*)((char*)Ks + bo + swz(row, sc * 2)) = krA[i];
#pragma unroll
          for (int qq = 0; qq < 8; ++qq) {
            int d = sc + qq;
            *(u16*)((char*)Vt + bo + d * 128 + ((2 * row) ^ ((d & 7) << 4))) =
                vrA[i][qq];
          }
        }
      } else {
#pragma unroll
        for (int i = 0; i < 2; ++i) {
          int row = i * 32 + srow;
          *(u16x8*)((char*)Ks + bo + swz(row, sc * 2)) = krB[i];
#pragma unroll
          for (int qq = 0; qq < 8; ++qq) {
            int d = sc + qq;
            *(u16*)((char*)Vt + bo + d * 128 + ((2 * row) ^ ((d & 7) << 4))) =
                vrB[i][qq];
          }
        }
      }
      if (tix + 1 < nt) {
        const int jn = (((qt <= 3) ? (tix + 1) : (qt - 2 + tix)) * 64) * 64;
        if ((tix & 1) == 0) {
          krB[0] = *(const u16x8*)(Kg + jn);
          krB[1] = *(const u16x8*)(Kg + jn + 2048);
          vrB[0] = *(const u16x8*)(Vg + jn);
          vrB[1] = *(const u16x8*)(Vg + jn + 2048);
        } else {
          krA[0] = *(const u16x8*)(Kg + jn);
          krA[1] = *(const u16x8*)(Kg + jn + 2048);
          vrA[0] = *(const u16x8*)(Vg + jn);
          vrA[1] = *(const u16x8*)(Vg + jn + 2048);
        }
      }
      LGKM0;
      BARR();

      f32x4 S[4] = {};
#pragma unroll
      for (int kk = 0; kk < 2; ++kk)
#pragma unroll
        for (int n = 0; n < 4; ++n) {
          bf16x8 kf = __builtin_bit_cast(
              bf16x8, *(const u16x8*)((char*)Ks + bo +
                                      swz(n * 16 + r, kk * 64 + g * 16)));
          S[n] = MFMA16(qf[kk], kf, S[n], 0, 0, 0);
        }

      float mloc[4] = {-1e30f, -1e30f, -1e30f, -1e30f};
#pragma unroll
      for (int n = 0; n < 4; ++n) {
        int j = j0 + n * 16 + r;
#pragma unroll
        for (int q = 0; q < 4; ++q) {
          int i = q0 + w * 16 + g * 4 + q;
          bool ok = (j <= i) && (((i - j) <= 128) || (j < 16));
          float s = ok ? S[n][q] * 0.125f : -1e30f;
          S[n][q] = s;
          mloc[q] = fmaxf(mloc[q], s);
        }
      }
#pragma unroll
      for (int q = 0; q < 4; ++q)
#pragma unroll
        for (int off = 1; off < 16; off <<= 1)
          mloc[q] = fmaxf(mloc[q], __shfl_xor(mloc[q], off));

      float alpha[4], rsum[4] = {};
#pragma unroll
      for (int q = 0; q < 4; ++q) {
        float mn = fmaxf(m_run[q], mloc[q]);
        alpha[q] = __expf(m_run[q] - mn);
        m_run[q] = mn;
      }
#pragma unroll
      for (int n = 0; n < 4; ++n)
#pragma unroll
        for (int q = 0; q < 4; ++q) {
          float p = __expf(S[n][q] - m_run[q]);
          S[n][q] = p;
          rsum[q] += p;
        }
#pragma unroll
      for (int q = 0; q < 4; ++q) {
#pragma unroll
        for (int off = 1; off < 16; off <<= 1)
          rsum[q] += __shfl_xor(rsum[q], off);
        l_run[q] = l_run[q] * alpha[q] + rsum[q];
      }
#pragma unroll
      for (int n = 0; n < 4; ++n) {
        acc[n][0] *= alpha[0];
        acc[n][1] *= alpha[1];
        acc[n][2] *= alpha[2];
        acc[n][3] *= alpha[3];
      }

#pragma unroll
      for (int n = 0; n < 4; ++n)
#pragma unroll
        for (int q = 0; q < 4; ++q)
          *((u16*)((char*)Pl + w * 2304 + (g * 4 + q) * 144) + (n * 16 + r)) =
              f2bf(S[n][q]);

#pragma unroll
      for (int kk = 0; kk < 2; ++kk) {
        bf16x8 pf = __builtin_bit_cast(
            bf16x8, *(const u16x8*)((char*)Pl + w * 2304 + r * 144 + kk * 64 +
                                    g * 16));
#pragma unroll
        for (int n = 0; n < 4; ++n) {
          bf16x8 vf = __builtin_bit_cast(
              bf16x8, *(const u16x8*)((char*)Vt + bo +
                                      swz(n * 16 + r, kk * 64 + g * 16)));
          acc[n] = MFMA16(pf, vf, acc[n], 0, 0, 0);
        }
      }
    }
  }

#pragma unroll
  for (int n = 0; n < 4; ++n)
#pragma unroll
    for (int q = 0; q < 4; ++q) {
      int s = q0 + w * 16 + g * 4 + q;
      int d = n * 16 + r;
      O[(b * 2048 + s) * 1024 + h * 64 + d] = f2bf(acc[n][q] / l_run[q]);
    }
}

// ---------------------------------------------------------------------------
extern "C" void kernel_launch(void* const* d_in, const int* in_sizes, int n_in,
                              void* d_out, int out_size, void* d_ws,
                              size_t ws_size, hipStream_t stream) {
  const float* b_q = (const float*)d_in[4];
  const float* b_k = (const float*)d_in[6];
  const float* b_v = (const float*)d_in[8];
  const float* b_o = (const float*)d_in[10];

  u16* ws = (u16*)d_ws;
  // ws (u16): Wq 0 | Wk 1M | Wv 2M | Wo 3M | Xq 4M | Xk 8M | Xv 12M |
  //           Qw 16M | Kw 20M | Vw 24M | Aw aliases Xq (4M)
  u16* Qw = ws + 16777216;
  u16* Kw = ws + 20971520;
  u16* Vw = ws + 25165824;
  u16* Aw = ws + 4194304;  // aliases Xq (dead after qkv projection)

  cast_all<<<dim3(8192), dim3(256), 0, stream>>>(
      (const float*)d_in[0], (const float*)d_in[1], (const float*)d_in[2],
      (const float*)d_in[3], (const float*)d_in[5], (const float*)d_in[7],
      (const float*)d_in[9], ws);
  qkv_gemm128<<<dim3(768), dim3(256), 0, stream>>>(ws, b_q, b_k, b_v, Qw, Kw,
                                                   Vw);
  attn_kernel<<<dim3(32, 16, 2), dim3(256), 0, stream>>>(Qw, Kw, Vw, Aw);
  out_gemm64<<<dim3(512), dim3(256), 0, stream>>>(Aw, ws + 3145728, b_o,
                                                  (float*)d_out);
}

// Round 13
// 89.060 us; speedup vs baseline: 1.1157x; 1.0087x over previous
//
#include <hip/hip_runtime.h>

typedef unsigned short u16;
typedef u16 u16x8 __attribute__((ext_vector_type(8)));
typedef __bf16 bf16x8 __attribute__((ext_vector_type(8)));
typedef float f32x4 __attribute__((ext_vector_type(4)));

#define MFMA16 __builtin_amdgcn_mfma_f32_16x16x32_bf16

__device__ __forceinline__ u16 f2bf(float f) {
  unsigned u = __builtin_bit_cast(unsigned, f);
  u += 0x7FFFu + ((u >> 16) & 1u);
  return (u16)(u >> 16);
}

// XOR-swizzled LDS byte address for 64-bf16 (128B) rows (guide G4).
__device__ __forceinline__ int swz(int row, int bcol) {
  return row * 128 + (bcol ^ ((row & 7) << 4));
}

__device__ __forceinline__ void gl16(const u16* g, u16* l) {
  __builtin_amdgcn_global_load_lds(
      (const __attribute__((address_space(1))) unsigned int*)g,
      (__attribute__((address_space(3))) unsigned int*)l, 16, 0, 0);
}

// raw workgroup barrier (no forced vmcnt(0) drain)
__device__ __forceinline__ void BARR() {
  asm volatile("" ::: "memory");
  __builtin_amdgcn_s_barrier();
  asm volatile("" ::: "memory");
}
#define VMCNT(n) asm volatile("s_waitcnt vmcnt(" #n ")" ::: "memory")
#define LGKM0 asm volatile("s_waitcnt lgkmcnt(0)" ::: "memory")

// ---------------------------------------------------------------------------
// Flattened fp32 -> bf16 cast. 16M elements total, 8/thread, 8192 blocks.
// ws layout (u16): Wq 0 | Wk 1M | Wv 2M | Wo 3M | Xq 4M | Xk 8M | Xv 12M
// ---------------------------------------------------------------------------
__global__ __launch_bounds__(256)
void cast_all(const float* __restrict__ q, const float* __restrict__ k,
              const float* __restrict__ v, const float* __restrict__ wq,
              const float* __restrict__ wk, const float* __restrict__ wv,
              const float* __restrict__ wo, u16* __restrict__ ws) {
  const long i = ((long)blockIdx.x * 256 + threadIdx.x) * 8;
  const float* s;
  u16* d;
  if (i < 12582912) {  // X region (12M)
    const int seg = (int)(i >> 22);
    const float* xs = (seg == 0) ? q : (seg == 1) ? k : v;
    s = xs + (i & 4194303);
    d = ws + 4194304 + i;
  } else {  // weights (4M)
    const long j = i - 12582912;
    const int seg = (int)(j >> 20);
    const float* wsrc = (seg == 0) ? wq : (seg == 1) ? wk : (seg == 2) ? wv : wo;
    s = wsrc + (j & 1048575);
    d = ws + j;
  }
  float4 v0 = *(const float4*)s;
  float4 v1 = *(const float4*)(s + 4);
  u16x8 p = {f2bf(v0.x), f2bf(v0.y), f2bf(v0.z), f2bf(v0.w),
             f2bf(v1.x), f2bf(v1.y), f2bf(v1.z), f2bf(v1.w)};
  *(u16x8*)d = p;
}

// ---------------------------------------------------------------------------
// Shared 128x64-tile 2-phase counted-vmcnt GEMM core (r12-proven).
// 512-class grids, 48 KB LDS -> 3 blocks/CU resident; 4 waves (2m x 2n),
// per-wave C = 64x32, 16 MFMA/K-tile. Phases split by N (A read ONLY in ph1,
// so ph2's A[t+2] staging into the same buf is 1 barrier past A's last read):
//  ph1: STG B[t+1] (2 gl16) | dsr A(8)+B-n0(2) | 8 MFMA (m x n0) | bar
//  ph2: STG A[t+2] (4 gl16) | dsr B-n1(2)      | 8 MFMA (m x n1) | vmcnt(4) | bar
// vmcnt(4): leaves A[t+2] (4 newest) in flight; retires A[t+1]+B[t+1].
// Tail: t=14 -> vmcnt(0); t=15 no stage/wait.
// Prologue: A0(4), B0(2), A1(4); vmcnt(4) retires A0+B0.
// ---------------------------------------------------------------------------
#define ZSTGA(tt, j)                                                        \
  gl16(Ain + (m0 + (w << 5) + (j)*8 + (lane >> 3)) * 1024 + (tt)*64 +       \
           (((lane & 7) ^ (lane >> 3)) << 3),                               \
       (u16*)(sb + ((tt)&1) * 24576 + (w << 12) + ((j) << 10)))
#define ZSTGB(tt, j)                                                        \
  gl16(W + (n0 + (w << 4) + (j)*8 + (lane >> 3)) * 1024 + (tt)*64 +         \
           (((lane & 7) ^ (lane >> 3)) << 3),                               \
       (u16*)(sb + ((tt)&1) * 24576 + 16384 + (w << 11) + ((j) << 10)))
#define ZLDA()                                                              \
  _Pragma("unroll") for (int m = 0; m < 4; ++m) {                           \
    char* p = sb + bo + rowAb + m * 2048;                                   \
    af[0][m] = __builtin_bit_cast(bf16x8, *(const u16x8*)(p + colr0));      \
    af[1][m] = __builtin_bit_cast(bf16x8, *(const u16x8*)(p + colr1));      \
  }
#define ZLDB(n)                                                             \
  {                                                                         \
    char* p = sb + bo + rowBb + (n)*2048;                                   \
    bf[0][n] = __builtin_bit_cast(bf16x8, *(const u16x8*)(p + colr0));      \
    bf[1][n] = __builtin_bit_cast(bf16x8, *(const u16x8*)(p + colr1));      \
  }
#define ZFMA(n)                                                             \
  __builtin_amdgcn_s_setprio(1);                                            \
  _Pragma("unroll") for (int m = 0; m < 4; ++m) {                           \
    acc[m][n] = MFMA16(af[0][m], bf[0][n], acc[m][n], 0, 0, 0);             \
    acc[m][n] = MFMA16(af[1][m], bf[1][n], acc[m][n], 0, 0, 0);             \
  }                                                                         \
  __builtin_amdgcn_s_setprio(0);

__device__ __forceinline__ void core64(const u16* __restrict__ Ain,
                                       const u16* __restrict__ W, int m0,
                                       int n0, char* sb, f32x4 (&acc)[4][2]) {
  const int tid = threadIdx.x, lane = tid & 63, w = tid >> 6;
  const int wm = w >> 1, wn = w & 1;
  const int r = lane & 15, g = lane >> 4;
  bf16x8 af[2][4], bf[2][2];

  const int colr0 = (g * 16) ^ ((r & 7) << 4);
  const int colr1 = (64 + g * 16) ^ ((r & 7) << 4);
  const int rowAb = (wm * 64 + r) * 128;
  const int rowBb = 16384 + (wn * 32 + r) * 128;

  // prologue: A0(4), B0(2), A1(4); A1 stays in flight
#pragma unroll
  for (int j = 0; j < 4; ++j) ZSTGA(0, j);
#pragma unroll
  for (int j = 0; j < 2; ++j) ZSTGB(0, j);
#pragma unroll
  for (int j = 0; j < 4; ++j) ZSTGA(1, j);
  VMCNT(4);
  __builtin_amdgcn_s_barrier();
  asm volatile("" ::: "memory");

  for (int t = 0; t < 16; ++t) {
    const int bo = (t & 1) * 24576;
    // ---- phase 1: all A + B-n0
    if (t < 15) { ZSTGB(t + 1, 0); ZSTGB(t + 1, 1); }
    ZLDA();
    ZLDB(0);
    ZFMA(0);
    BARR();
    // ---- phase 2: B-n1 only (A region not read -> A[t+2] staging safe)
    if (t < 14) { ZSTGA(t + 2, 0); ZSTGA(t + 2, 1); ZSTGA(t + 2, 2); ZSTGA(t + 2, 3); }
    ZLDB(1);
    ZFMA(1);
    if (t < 14) { VMCNT(4); } else if (t == 14) { VMCNT(0); }
    BARR();
  }
}

// ---------------------------------------------------------------------------
// QKV projection: 1536 blocks (3 z * 32 m * 16 n), 128x64 tile, 3 blocks/CU
// resident (2 full-residency rounds). Same core as out projection.
// ---------------------------------------------------------------------------
__global__ __launch_bounds__(256)
void qkv_gemm64(const u16* __restrict__ ws_in, const float* __restrict__ c0,
                const float* __restrict__ c1, const float* __restrict__ c2,
                u16* __restrict__ o0, u16* __restrict__ o1,
                u16* __restrict__ o2) {
  const int bid = blockIdx.x;
  const int s = (bid & 7) * 192 + (bid >> 3);  // XCD swizzle, 1536 % 8 == 0
  const int z = s / 512;
  const int rem = s & 511;
  const int m0 = (rem >> 4) << 7;  // 32 m-tiles of 128
  const int n0 = (rem & 15) << 6;  // 16 n-tiles of 64

  const u16* __restrict__ Ain = ws_in + 4194304 + z * 4194304;
  const u16* __restrict__ W = ws_in + z * 1048576;
  const float* Bi = (z == 0) ? c0 : (z == 1) ? c1 : c2;
  u16* O = (z == 0) ? o0 : (z == 1) ? o1 : o2;

  const int tid = threadIdx.x, lane = tid & 63, w = tid >> 6;
  const int wm = w >> 1, wn = w & 1;
  const int r = lane & 15, g = lane >> 4;

  __shared__ u16 SH[24576];  // 48 KB
  f32x4 acc[4][2] = {};
  core64(Ain, W, m0, n0, (char*)SH, acc);

  // epilogue -> bf16 [B,H,S,64]; C/D layout col=lane&15, row=g*4+q
#pragma unroll
  for (int n = 0; n < 2; ++n) {
    const int gn = n0 + wn * 32 + n * 16 + r;
    const int hh = gn >> 6, d = gn & 63;
    const float bv = Bi[gn];
#pragma unroll
    for (int m = 0; m < 4; ++m) {
#pragma unroll
      for (int q = 0; q < 4; ++q) {
        int gm = m0 + wm * 64 + m * 16 + g * 4 + q;
        int bb = gm >> 11, sIdx = gm & 2047;
        O[((bb * 16 + hh) * 2048 + sIdx) * 64 + d] = f2bf(acc[m][n][q] + bv);
      }
    }
  }
}

// ---------------------------------------------------------------------------
// Output projection: 512 blocks (32 m * 16 n), 128x64 tile, fp32 out.
// ---------------------------------------------------------------------------
__global__ __launch_bounds__(256)
void out_gemm64(const u16* __restrict__ Ain, const u16* __restrict__ W,
                const float* __restrict__ Bi, float* __restrict__ C) {
  const int bid = blockIdx.x;
  const int s = (bid & 7) * 64 + (bid >> 3);  // XCD swizzle, 512 % 8 == 0
  const int m0 = (s >> 4) << 7;  // 32 m-tiles of 128
  const int n0 = (s & 15) << 6;  // 16 n-tiles of 64

  const int tid = threadIdx.x, lane = tid & 63, w = tid >> 6;
  const int wm = w >> 1, wn = w & 1;
  const int r = lane & 15, g = lane >> 4;

  __shared__ u16 SH[24576];  // 48 KB
  f32x4 acc[4][2] = {};
  core64(Ain, W, m0, n0, (char*)SH, acc);

  // epilogue: fp32 C + bias
#pragma unroll
  for (int m = 0; m < 4; ++m) {
#pragma unroll
    for (int n = 0; n < 2; ++n) {
      int gn = n0 + wn * 32 + n * 16 + r;
      float bv = Bi[gn];
#pragma unroll
      for (int q = 0; q < 4; ++q) {
        int gm = m0 + wm * 64 + m * 16 + g * 4 + q;
        C[gm * 1024 + gn] = acc[m][n][q] + bv;
      }
    }
  }
}

// ---------------------------------------------------------------------------
// Sparse flash attention (r8 version, T14 async-stage + dbuf K/V).
// grid (32 qtiles, 16 heads, 2 batch), 256 threads (4 waves x 16 q-rows).
// ---------------------------------------------------------------------------
__global__ __launch_bounds__(256)
void attn_kernel(const u16* __restrict__ Q, const u16* __restrict__ K,
                 const u16* __restrict__ V, u16* __restrict__ O) {
  const int qt = blockIdx.x, h = blockIdx.y, b = blockIdx.z;
  const int tid = threadIdx.x, lane = tid & 63, w = tid >> 6;
  const int r = lane & 15, g = lane >> 4;
  const int q0 = qt * 64;
  const int base = (b * 16 + h) * 131072;
  const u16* Qb = Q + base;

  __shared__ u16 Ks[2][4096];
  __shared__ u16 Vt[2][4096];  // transposed: Vt[d][j]
  __shared__ u16 Pl[4608];     // 4 waves x 16 rows x 144B stride

  bf16x8 qf[2];
  {
    const u16* qp = Qb + (q0 + w * 16 + r) * 64 + g * 8;
    qf[0] = __builtin_bit_cast(bf16x8, *(const u16x8*)qp);
    qf[1] = __builtin_bit_cast(bf16x8, *(const u16x8*)(qp + 32));
  }

  f32x4 acc[4] = {};
  float m_run[4] = {-1e30f, -1e30f, -1e30f, -1e30f};
  float l_run[4] = {};

  const int nt = (qt <= 3) ? (qt + 1) : 4;
  const int srow = tid >> 3, sc = (tid & 7) * 8;
  const u16* Kg = K + base + srow * 64 + sc;
  const u16* Vg = V + base + srow * 64 + sc;

  u16x8 krA[2], vrA[2], krB[2], vrB[2];
  krA[0] = *(const u16x8*)(Kg);
  krA[1] = *(const u16x8*)(Kg + 2048);
  vrA[0] = *(const u16x8*)(Vg);
  vrA[1] = *(const u16x8*)(Vg + 2048);

#pragma unroll
  for (int tix = 0; tix < 4; ++tix) {
    if (tix < nt) {
      const int j0 = ((tix == 0) ? 0 : ((qt <= 3) ? tix : (qt - 3 + tix))) * 64;
      const int bo = (tix & 1) * 8192;
      if ((tix & 1) == 0) {
#pragma unroll
        for (int i = 0; i < 2; ++i) {
          int row = i * 32 + srow;
          *(u16x8*)((char*)Ks + bo + swz(row, sc * 2)) = krA[i];
#pragma unroll
          for (int qq = 0; qq < 8; ++qq) {
            int d = sc + qq;
            *(u16*)((char*)Vt + bo + d * 128 + ((2 * row) ^ ((d & 7) << 4))) =
                vrA[i][qq];
          }
        }
      } else {
#pragma unroll
        for (int i = 0; i < 2; ++i) {
          int row = i * 32 + srow;
          *(u16x8*)((char*)Ks + bo + swz(row, sc * 2)) = krB[i];
#pragma unroll
          for (int qq = 0; qq < 8; ++qq) {
            int d = sc + qq;
            *(u16*)((char*)Vt + bo + d * 128 + ((2 * row) ^ ((d & 7) << 4))) =
                vrB[i][qq];
          }
        }
      }
      if (tix + 1 < nt) {
        const int jn = (((qt <= 3) ? (tix + 1) : (qt - 2 + tix)) * 64) * 64;
        if ((tix & 1) == 0) {
          krB[0] = *(const u16x8*)(Kg + jn);
          krB[1] = *(const u16x8*)(Kg + jn + 2048);
          vrB[0] = *(const u16x8*)(Vg + jn);
          vrB[1] = *(const u16x8*)(Vg + jn + 2048);
        } else {
          krA[0] = *(const u16x8*)(Kg + jn);
          krA[1] = *(const u16x8*)(Kg + jn + 2048);
          vrA[0] = *(const u16x8*)(Vg + jn);
          vrA[1] = *(const u16x8*)(Vg + jn + 2048);
        }
      }
      LGKM0;
      BARR();

      f32x4 S[4] = {};
#pragma unroll
      for (int kk = 0; kk < 2; ++kk)
#pragma unroll
        for (int n = 0; n < 4; ++n) {
          bf16x8 kf = __builtin_bit_cast(
              bf16x8, *(const u16x8*)((char*)Ks + bo +
                                      swz(n * 16 + r, kk * 64 + g * 16)));
          S[n] = MFMA16(qf[kk], kf, S[n], 0, 0, 0);
        }

      float mloc[4] = {-1e30f, -1e30f, -1e30f, -1e30f};
#pragma unroll
      for (int n = 0; n < 4; ++n) {
        int j = j0 + n * 16 + r;
#pragma unroll
        for (int q = 0; q < 4; ++q) {
          int i = q0 + w * 16 + g * 4 + q;
          bool ok = (j <= i) && (((i - j) <= 128) || (j < 16));
          float s = ok ? S[n][q] * 0.125f : -1e30f;
          S[n][q] = s;
          mloc[q] = fmaxf(mloc[q], s);
        }
      }
#pragma unroll
      for (int q = 0; q < 4; ++q)
#pragma unroll
        for (int off = 1; off < 16; off <<= 1)
          mloc[q] = fmaxf(mloc[q], __shfl_xor(mloc[q], off));

      float alpha[4], rsum[4] = {};
#pragma unroll
      for (int q = 0; q < 4; ++q) {
        float mn = fmaxf(m_run[q], mloc[q]);
        alpha[q] = __expf(m_run[q] - mn);
        m_run[q] = mn;
      }
#pragma unroll
      for (int n = 0; n < 4; ++n)
#pragma unroll
        for (int q = 0; q < 4; ++q) {
          float p = __expf(S[n][q] - m_run[q]);
          S[n][q] = p;
          rsum[q] += p;
        }
#pragma unroll
      for (int q = 0; q < 4; ++q) {
#pragma unroll
        for (int off = 1; off < 16; off <<= 1)
          rsum[q] += __shfl_xor(rsum[q], off);
        l_run[q] = l_run[q] * alpha[q] + rsum[q];
      }
#pragma unroll
      for (int n = 0; n < 4; ++n) {
        acc[n][0] *= alpha[0];
        acc[n][1] *= alpha[1];
        acc[n][2] *= alpha[2];
        acc[n][3] *= alpha[3];
      }

#pragma unroll
      for (int n = 0; n < 4; ++n)
#pragma unroll
        for (int q = 0; q < 4; ++q)
          *((u16*)((char*)Pl + w * 2304 + (g * 4 + q) * 144) + (n * 16 + r)) =
              f2bf(S[n][q]);

#pragma unroll
      for (int kk = 0; kk < 2; ++kk) {
        bf16x8 pf = __builtin_bit_cast(
            bf16x8, *(const u16x8*)((char*)Pl + w * 2304 + r * 144 + kk * 64 +
                                    g * 16));
#pragma unroll
        for (int n = 0; n < 4; ++n) {
          bf16x8 vf = __builtin_bit_cast(
              bf16x8, *(const u16x8*)((char*)Vt + bo +
                                      swz(n * 16 + r, kk * 64 + g * 16)));
          acc[n] = MFMA16(pf, vf, acc[n], 0, 0, 0);
        }
      }
    }
  }

#pragma unroll
  for (int n = 0; n < 4; ++n)
#pragma unroll
    for (int q = 0; q < 4; ++q) {
      int s = q0 + w * 16 + g * 4 + q;
      int d = n * 16 + r;
      O[(b * 2048 + s) * 1024 + h * 64 + d] = f2bf(acc[n][q] / l_run[q]);
    }
}

// ---------------------------------------------------------------------------
extern "C" void kernel_launch(void* const* d_in, const int* in_sizes, int n_in,
                              void* d_out, int out_size, void* d_ws,
                              size_t ws_size, hipStream_t stream) {
  const float* b_q = (const float*)d_in[4];
  const float* b_k = (const float*)d_in[6];
  const float* b_v = (const float*)d_in[8];
  const float* b_o = (const float*)d_in[10];

  u16* ws = (u16*)d_ws;
  // ws (u16): Wq 0 | Wk 1M | Wv 2M | Wo 3M | Xq 4M | Xk 8M | Xv 12M |
  //           Qw 16M | Kw 20M | Vw 24M | Aw aliases Xq (4M)
  u16* Qw = ws + 16777216;
  u16* Kw = ws + 20971520;
  u16* Vw = ws + 25165824;
  u16* Aw = ws + 4194304;  // aliases Xq (dead after qkv projection)

  cast_all<<<dim3(8192), dim3(256), 0, stream>>>(
      (const float*)d_in[0], (const float*)d_in[1], (const float*)d_in[2],
      (const float*)d_in[3], (const float*)d_in[5], (const float*)d_in[7],
      (const float*)d_in[9], ws);
  qkv_gemm64<<<dim3(1536), dim3(256), 0, stream>>>(ws, b_q, b_k, b_v, Qw, Kw,
                                                   Vw);
  attn_kernel<<<dim3(32, 16, 2), dim3(256), 0, stream>>>(Qw, Kw, Vw, Aw);
  out_gemm64<<<dim3(512), dim3(256), 0, stream>>>(Aw, ws + 3145728, b_o,
                                                  (float*)d_out);
}